// Round 1
// baseline (370.152 us; speedup 1.0000x reference)
//
#include <hip/hip_runtime.h>

typedef unsigned short u16;
typedef unsigned int u32;
typedef __attribute__((ext_vector_type(4))) float floatx4;
typedef __attribute__((ext_vector_type(8))) __bf16 bf16x8;

#define MFMA_BF16(a, b, c) __builtin_amdgcn_mfma_f32_16x16x32_bf16((a), (b), (c), 0, 0, 0)

typedef const __attribute__((address_space(1))) void* gas_ptr;
typedef __attribute__((address_space(3))) void* las_ptr;

__device__ __forceinline__ void gll16(const void* g, void* l) {
  __builtin_amdgcn_global_load_lds((gas_ptr)g, (las_ptr)l, 16, 0, 0);
}

__device__ __forceinline__ u16 f2bf(float x) {
  u32 u = __builtin_bit_cast(u32, x);
  u = (u + 0x7fffu + ((u >> 16) & 1u)) >> 16;
  return (u16)u;
}

// ---------------------------------------------------------------------------
// Kernel 1: down/up vectors from palette.  down[w][r][k], up[w][n][r] (fp32)
// 4 weights x (5120 down rows + 5120 up rows) = 40960 threads, 15 MACs each.
// ---------------------------------------------------------------------------
__global__ void prep_downup(const float* __restrict__ pal,
                            const float* __restrict__ qd, const float* __restrict__ qu,
                            const float* __restrict__ kd, const float* __restrict__ ku,
                            const float* __restrict__ vd, const float* __restrict__ vu,
                            const float* __restrict__ od, const float* __restrict__ ou,
                            float* __restrict__ down_f, float* __restrict__ up_f) {
  int tid = blockIdx.x * blockDim.x + threadIdx.x;
  int w = tid / 10240;
  int rem = tid - w * 10240;
  const float* dsrc = (w == 0) ? qd : (w == 1) ? kd : (w == 2) ? vd : od;
  const float* usrc = (w == 0) ? qu : (w == 1) ? ku : (w == 2) ? vu : ou;
  bool isdown = rem < 5120;
  int row = isdown ? rem : rem - 5120;
  const float* src = (isdown ? dsrc : usrc) + row * 15;
  float s = 0.f;
#pragma unroll
  for (int p = 0; p < 15; ++p) s += pal[p] * src[p];
  if (isdown) down_f[w * 5120 + row] = s;
  else        up_f[w * 5120 + row] = s;
}

// ---------------------------------------------------------------------------
// Kernel 2: W_eff[n][k] = W[n][k] + sum_r up[n][r]*down[r][k], cast to bf16.
// weff_qkv is [3840][1280] (q rows 0..1279, k 1280..2559, v 2560..3839).
// ---------------------------------------------------------------------------
__global__ void build_weff(const float* __restrict__ Wq, const float* __restrict__ Wk,
                           const float* __restrict__ Wv, const float* __restrict__ Wo,
                           const float* __restrict__ down_f, const float* __restrict__ up_f,
                           u16* __restrict__ weff_qkv, u16* __restrict__ weff_o) {
  int tid = blockIdx.x * blockDim.x + threadIdx.x;  // 4 * 1638400
  int w = tid / 1638400;
  int rem = tid - w * 1638400;
  int n = rem / 1280;
  int k = rem - n * 1280;
  const float* W = (w == 0) ? Wq : (w == 1) ? Wk : (w == 2) ? Wv : Wo;
  const float* up = up_f + w * 5120 + n * 4;
  const float* dn = down_f + w * 5120 + k;
  float v = W[rem] + up[0] * dn[0] + up[1] * dn[1280] + up[2] * dn[2560] + up[3] * dn[3840];
  u16 hv = f2bf(v);
  if (w < 3) weff_qkv[w * 1638400 + rem] = hv;
  else       weff_o[rem] = hv;
}

// ---------------------------------------------------------------------------
// Kernel 3: x fp32 -> bf16
// ---------------------------------------------------------------------------
__global__ void cvt_x(const float4* __restrict__ x, ushort4* __restrict__ xb) {
  int i = blockIdx.x * blockDim.x + threadIdx.x;  // 1310720
  float4 v = x[i];
  ushort4 o;
  o.x = f2bf(v.x); o.y = f2bf(v.y); o.z = f2bf(v.z); o.w = f2bf(v.w);
  xb[i] = o;
}

// ---------------------------------------------------------------------------
// m97-style bf16 GEMM: C[M,N] = A[M,K] @ B[N,K]^T.  128x128 tile, BK=32,
// 4 waves (2x2), each wave 64x64 = 4x4 grid of 16x16x32 MFMAs.
// MODE 0: QKV epilogue -> q/k bf16 natural [4096][1280], v transposed
//         vt[(b*1280 + n')*2048 + s] bf16.
// MODE 1: O-proj epilogue -> fp32 out + bias.
// ---------------------------------------------------------------------------
template <int MODE>
__global__ __launch_bounds__(256) void gemm128(const u16* __restrict__ A, const u16* __restrict__ Bm,
                                               u16* __restrict__ qb, u16* __restrict__ kb,
                                               u16* __restrict__ vtb, float* __restrict__ outf,
                                               const float* __restrict__ bias, int K) {
  __shared__ __align__(16) u16 lA[128 * 32];
  __shared__ __align__(16) u16 lB[128 * 32];
  const int t = threadIdx.x;
  const int lane = t & 63;
  const int l15 = lane & 15, quad = lane >> 4;
  const int wid = t >> 6;
  const int wm = (wid >> 1) * 64;
  const int wn = (wid & 1) * 64;
  const int bm = blockIdx.x * 128;
  const int bn = blockIdx.y * 128;
  floatx4 acc[4][4] = {};

  const int r0 = t >> 2;          // chunk t      -> rows 0..63
  const int r1 = (t >> 2) + 64;   // chunk t+256  -> rows 64..127
  const int kc = t & 3;
  const u16* Ab = A + (long)bm * K;
  const u16* Bb = Bm + (long)bn * K;
  const int nkt = K >> 5;

  for (int kt = 0; kt < nkt; ++kt) {
    __syncthreads();
    const int k0 = kt * 32 + kc * 8;
    gll16(Ab + (long)r0 * K + k0, lA + t * 8);
    gll16(Ab + (long)r1 * K + k0, lA + (t + 256) * 8);
    gll16(Bb + (long)r0 * K + k0, lB + t * 8);
    gll16(Bb + (long)r1 * K + k0, lB + (t + 256) * 8);
    __syncthreads();
    bf16x8 af[4], bfr[4];
#pragma unroll
    for (int i = 0; i < 4; ++i)
      af[i] = *(const bf16x8*)(lA + (wm + i * 16 + l15) * 32 + quad * 8);
#pragma unroll
    for (int i = 0; i < 4; ++i)
      bfr[i] = *(const bf16x8*)(lB + (wn + i * 16 + l15) * 32 + quad * 8);
#pragma unroll
    for (int i = 0; i < 4; ++i)
#pragma unroll
      for (int j = 0; j < 4; ++j)
        acc[i][j] = MFMA_BF16(af[i], bfr[j], acc[i][j]);
  }

#pragma unroll
  for (int i = 0; i < 4; ++i) {
#pragma unroll
    for (int j = 0; j < 4; ++j) {
#pragma unroll
      for (int r = 0; r < 4; ++r) {
        int m = bm + wm + i * 16 + quad * 4 + r;
        int n = bn + wn + j * 16 + l15;
        float v = acc[i][j][r];
        if (MODE == 1) {
          outf[(long)m * 1280 + n] = v + bias[n];
        } else {
          u16 hv = f2bf(v);
          if (n < 1280) {
            qb[(long)m * 1280 + n] = hv;
          } else if (n < 2560) {
            kb[(long)m * 1280 + (n - 1280)] = hv;
          } else {
            int np = n - 2560;
            int b = m >> 11, s = m & 2047;
            vtb[((long)(b * 1280 + np)) * 2048 + s] = hv;
          }
        }
      }
    }
  }
}

// ---------------------------------------------------------------------------
// Flash attention.  Grid (S/64, B*H), 256 threads = 4 waves, 16 q-rows/wave.
// K-tile [64][160] bf16 (natural), Vt-tile [160][72-stride] bf16 (transposed,
// padded for bank uniformity), P through LDS fp32 [16][36]/wave.
// ---------------------------------------------------------------------------
__global__ __launch_bounds__(256) void flash_attn(const u16* __restrict__ qb,
                                                  const u16* __restrict__ kb,
                                                  const u16* __restrict__ vtb,
                                                  u16* __restrict__ attn) {
  const int S = 2048, D = 1280, HD = 160;
  __shared__ __align__(16) u16 kt_lds[64 * 160];
  __shared__ __align__(16) u16 vt_lds[160 * 72];
  __shared__ __align__(16) float p_lds[4][16 * 36];
  const int t = threadIdx.x, lane = t & 63, wid = t >> 6;
  const int quad = lane >> 4, l15 = lane & 15;
  const int bh = blockIdx.y, b = bh >> 3, h = bh & 7;
  const int q0 = blockIdx.x * 64 + wid * 16;
  const float scale = 0.079056941504f;  // 1/sqrt(160)

  bf16x8 aq[5];
  {
    const u16* qg = qb + ((long)(b * 2048 + q0 + l15)) * D + h * HD + quad * 8;
#pragma unroll
    for (int dc = 0; dc < 5; ++dc) aq[dc] = *(const bf16x8*)(qg + dc * 32);
  }
  float m_i[4] = {-1e30f, -1e30f, -1e30f, -1e30f};
  float l_i[4] = {0.f, 0.f, 0.f, 0.f};
  floatx4 o_acc[10] = {};
  const u16* kgbase = kb + ((long)(b * 2048)) * D + h * HD;
  const u16* vgbase = vtb + ((long)(b * 1280 + h * HD)) * 2048;

  for (int kt0 = 0; kt0 < S; kt0 += 64) {
    __syncthreads();
#pragma unroll
    for (int i = 0; i < 5; ++i) {  // K-tile: 1280 chunks of 16B
      int c = t + i * 256;
      int row = c / 20, dcol = (c % 20) * 8;
      gll16(kgbase + (long)(kt0 + row) * D + dcol, kt_lds + c * 8);
    }
#pragma unroll
    for (int i = 0; i < 5; ++i) {  // Vt-tile: 160 rows x 64, stride 72
      int c = t + i * 256;
      int row = c >> 3, scol = (c & 7) * 8;
      float4 vv = *(const float4*)(vgbase + (long)row * 2048 + kt0 + scol);
      *(float4*)(vt_lds + row * 72 + scol) = vv;
    }
    __syncthreads();
#pragma unroll
    for (int ks = 0; ks < 2; ++ks) {
      const int kbase = ks * 32;
      floatx4 s0 = {0.f, 0.f, 0.f, 0.f}, s1 = {0.f, 0.f, 0.f, 0.f};
#pragma unroll
      for (int dc = 0; dc < 5; ++dc) {
        bf16x8 kf0 = *(const bf16x8*)(kt_lds + (kbase + l15) * 160 + dc * 32 + quad * 8);
        bf16x8 kf1 = *(const bf16x8*)(kt_lds + (kbase + 16 + l15) * 160 + dc * 32 + quad * 8);
        s0 = MFMA_BF16(aq[dc], kf0, s0);
        s1 = MFMA_BF16(aq[dc], kf1, s1);
      }
#pragma unroll
      for (int r = 0; r < 4; ++r) {
        float v0 = s0[r] * scale, v1 = s1[r] * scale;
        float mc = fmaxf(v0, v1);
        mc = fmaxf(mc, __shfl_xor(mc, 1, 64));
        mc = fmaxf(mc, __shfl_xor(mc, 2, 64));
        mc = fmaxf(mc, __shfl_xor(mc, 4, 64));
        mc = fmaxf(mc, __shfl_xor(mc, 8, 64));
        float mn = fmaxf(m_i[r], mc);
        float alpha = __expf(m_i[r] - mn);
        float p0 = __expf(v0 - mn), p1 = __expf(v1 - mn);
        float rs = p0 + p1;
        rs += __shfl_xor(rs, 1, 64);
        rs += __shfl_xor(rs, 2, 64);
        rs += __shfl_xor(rs, 4, 64);
        rs += __shfl_xor(rs, 8, 64);
        l_i[r] = l_i[r] * alpha + rs;
        m_i[r] = mn;
        int prow = quad * 4 + r;
        p_lds[wid][prow * 36 + l15] = p0;
        p_lds[wid][prow * 36 + 16 + l15] = p1;
#pragma unroll
        for (int dc = 0; dc < 10; ++dc) o_acc[dc][r] *= alpha;
      }
      asm volatile("s_waitcnt lgkmcnt(0)" ::: "memory");  // cross-lane P via LDS
      float4 pa0 = *(const float4*)(&p_lds[wid][l15 * 36 + quad * 8]);
      float4 pa1 = *(const float4*)(&p_lds[wid][l15 * 36 + quad * 8 + 4]);
      bf16x8 pa;
      pa[0] = (__bf16)pa0.x; pa[1] = (__bf16)pa0.y; pa[2] = (__bf16)pa0.z; pa[3] = (__bf16)pa0.w;
      pa[4] = (__bf16)pa1.x; pa[5] = (__bf16)pa1.y; pa[6] = (__bf16)pa1.z; pa[7] = (__bf16)pa1.w;
#pragma unroll
      for (int dc = 0; dc < 10; ++dc) {
        bf16x8 vf = *(const bf16x8*)(vt_lds + (dc * 16 + l15) * 72 + kbase + quad * 8);
        o_acc[dc] = MFMA_BF16(pa, vf, o_acc[dc]);
      }
    }
  }
#pragma unroll
  for (int dc = 0; dc < 10; ++dc) {
#pragma unroll
    for (int r = 0; r < 4; ++r) {
      float v = o_acc[dc][r] / l_i[r];
      int row = q0 + quad * 4 + r;
      int col = h * HD + dc * 16 + l15;
      attn[((long)(b * 2048 + row)) * D + col] = f2bf(v);
    }
  }
}

// ---------------------------------------------------------------------------
// Launcher.  Workspace layout (bytes):
//   xb      @ 0         (10485760)  x bf16 [4096][1280]
//   weffqkv @ 10485760  ( 9830400)  [3840][1280] bf16
//   weffo   @ 20316160  ( 3276800)  [1280][1280] bf16
//   qbuf    @ 23592960  (10485760)
//   kbuf    @ 34078720  (10485760)
//   vtb     @ 44564480  (10485760)  V transposed [B][1280][2048]
//   attn    @ 55050240  (10485760)
//   down_f  @ 65536000  (   81920)
//   up_f    @ 65617920  (   81920)   total ~62.7 MB
// ---------------------------------------------------------------------------
extern "C" void kernel_launch(void* const* d_in, const int* in_sizes, int n_in,
                              void* d_out, int out_size, void* d_ws, size_t ws_size,
                              hipStream_t stream) {
  const float* x   = (const float*)d_in[0];
  const float* pal = (const float*)d_in[1];
  const float* Wq  = (const float*)d_in[2];
  const float* Wk  = (const float*)d_in[3];
  const float* Wv  = (const float*)d_in[4];
  const float* Wo  = (const float*)d_in[5];
  const float* bo  = (const float*)d_in[6];
  const float* qd  = (const float*)d_in[7];
  const float* qu  = (const float*)d_in[8];
  const float* kd  = (const float*)d_in[9];
  const float* ku  = (const float*)d_in[10];
  const float* vd  = (const float*)d_in[11];
  const float* vu  = (const float*)d_in[12];
  const float* od  = (const float*)d_in[13];
  const float* ou  = (const float*)d_in[14];
  float* out = (float*)d_out;

  char* ws = (char*)d_ws;
  u16* xb       = (u16*)(ws);
  u16* weff_qkv = (u16*)(ws + 10485760);
  u16* weff_o   = (u16*)(ws + 20316160);
  u16* qbuf     = (u16*)(ws + 23592960);
  u16* kbuf     = (u16*)(ws + 34078720);
  u16* vtb      = (u16*)(ws + 44564480);
  u16* attn     = (u16*)(ws + 55050240);
  float* down_f = (float*)(ws + 65536000);
  float* up_f   = (float*)(ws + 65617920);

  prep_downup<<<160, 256, 0, stream>>>(pal, qd, qu, kd, ku, vd, vu, od, ou, down_f, up_f);
  build_weff<<<25600, 256, 0, stream>>>(Wq, Wk, Wv, Wo, down_f, up_f, weff_qkv, weff_o);
  cvt_x<<<5120, 256, 0, stream>>>((const float4*)x, (ushort4*)xb);
  gemm128<0><<<dim3(32, 30), 256, 0, stream>>>(xb, weff_qkv, qbuf, kbuf, vtb, nullptr, nullptr, 1280);
  flash_attn<<<dim3(32, 16), 256, 0, stream>>>(qbuf, kbuf, vtb, attn);
  gemm128<1><<<dim3(32, 10), 256, 0, stream>>>(attn, weff_o, nullptr, nullptr, nullptr, out, bo, 1280);
}